// Round 19
// baseline (246.728 us; speedup 1.0000x reference)
//
#include <hip/hip_runtime.h>
#include <hip/hip_bf16.h>
#include <hip/hip_fp16.h>

#define NN 100000
#define NE 3200000
#define FIN 256
#define F1 16
#define F2 32
#define CO 64
#define NC 1000
#define NBLK 391   /* ceil(NN/256) */
#define GBLK 1563  /* ceil(NN/64) gemm1 grid (64-row tiles) */
#define NPART 8
#define NGRP 32    /* sub-segments (groups) per partition */
#define CAPG 16384 /* fixed capacity per (partition,group) sub-segment */
#define PSZ 12500  /* NN / NPART */
#define BK 20      /* edges per thread in bucket; 625 blocks * 256 * 20 = NE */
#define SRCMASK 0x1FFFFu   /* low 17 bits = src; high bits = dst_local */

// workspace layout (float offsets) — total 10,896,384 floats = 43.6 MB
#define OFF_DINV 0
#define OFF_CUR  100352
#define OFF_DEG  200704
#define OFF_ECOL 301056
#define OFF_MISC 3501056    /* pcur[256]@0, pool[64]@256, bsum[391]@320 (ends 711 < 1024) */
#define OFF_EPART 3502080   /* u32[256*16384] = 4,194,304 -> ends 7,696,384 */
#define OFF_HIST  7696384   /* u32[8*32*12500] = 3.2M -> ends 10,896,384 */
#define OFF_H1S   3502080   /* fp16, 800K floats (ends 4,302,080); overlays epart (dead after place) */
#define OFF_H2S   4302080   /* fp16, 1.6M floats (ends 5,902,080); overlays epart (dead after place) */
#define OFF_OUT2H 5902080   /* fp16, 1.6M floats (ends 7,502,080); overlays epart tail (dead after place) */

__device__ __forceinline__ unsigned enc_f(float f) {
    unsigned u = __float_as_uint(f);
    return (u & 0x80000000u) ? ~u : (u | 0x80000000u);
}
__device__ __forceinline__ float dec_f(unsigned u) {
    return (u & 0x80000000u) ? __uint_as_float(u & 0x7fffffffu) : __uint_as_float(~u);
}

// ---------- K0: init fixed sub-segment cursors + zero pool ----------
__global__ void k_init(unsigned* __restrict__ pcur, unsigned* __restrict__ pool) {
    int t = threadIdx.x;
    pcur[t] = (unsigned)t * CAPG;
    if (t < 64) pool[t] = 0u;
}

// ---------- K1: bucket edges into fixed-capacity (p,g) sub-segments, packed u32 ----------
__global__ __launch_bounds__(256) void k_bucket(const int* __restrict__ ei,
                                                unsigned* __restrict__ pcur,
                                                unsigned* __restrict__ epart) {
    __shared__ unsigned wcnt[4][8];
    __shared__ unsigned woff[4][8];
    int t = threadIdx.x, lane = t & 63, w = t >> 6;
    int g = blockIdx.x & (NGRP - 1);
    int base = blockIdx.x * (256 * BK) + t;
    int dst[BK], src[BK];
    #pragma unroll
    for (int k = 0; k < BK; ++k) {
        dst[k] = ei[NE + base + k * 256];
        src[k] = ei[base + k * 256];
    }
    unsigned long long lt = (lane == 63) ? 0x7fffffffffffffffull
                                         : ((1ull << lane) - 1ull);
    // sweep 1: per-wave per-bin counts (lane b tracks bin b)
    unsigned cnt = 0;
    #pragma unroll
    for (int k = 0; k < BK; ++k) {
        int bin = (unsigned)dst[k] / PSZ;
        #pragma unroll
        for (int b = 0; b < 8; ++b) {
            unsigned long long m = __ballot(bin == b);
            if (lane == b) cnt += (unsigned)__popcll(m);
        }
    }
    if (lane < 8) wcnt[w][lane] = cnt;
    __syncthreads();
    if (t < 8) {
        unsigned c0 = wcnt[0][t], c1 = wcnt[1][t], c2 = wcnt[2][t], c3 = wcnt[3][t];
        unsigned b = atomicAdd(&pcur[t * NGRP + g], c0 + c1 + c2 + c3);
        woff[0][t] = b;
        woff[1][t] = b + c0;
        woff[2][t] = b + c0 + c1;
        woff[3][t] = b + c0 + c1 + c2;
    }
    __syncthreads();
    unsigned run = (lane < 8) ? woff[w][lane] : 0u;
    // sweep 2: place packed (dst_local<<17 | src)
    #pragma unroll
    for (int k = 0; k < BK; ++k) {
        int bin = (unsigned)dst[k] / PSZ;
        unsigned long long mym = 0;
        unsigned myrun = 0;
        #pragma unroll
        for (int b = 0; b < 8; ++b) {
            unsigned long long m = __ballot(bin == b);
            unsigned r = __shfl(run, b);
            if (bin == b) { mym = m; myrun = r; }
            if (lane == b) run += (unsigned)__popcll(m);
        }
        unsigned pos = myrun + (unsigned)__popcll(mym & lt);
        epart[pos] = ((unsigned)(dst[k] - bin * PSZ) << 17) | (unsigned)src[k];
    }
}

// ---------- K2: per-(p,g) LDS histograms -> hist[p][g][i] ----------
__global__ __launch_bounds__(256) void k_hist(const unsigned* __restrict__ pcur,
                                              const unsigned* __restrict__ epart,
                                              unsigned* __restrict__ hist) {
    __shared__ unsigned lh[PSZ];
    int p = blockIdx.x & 7;
    int g = blockIdx.x >> 3;               // 0..NGRP-1
    int ci = p * NGRP + g;
    int t = threadIdx.x;
    for (int i = t; i < PSZ; i += 256) lh[i] = 0;
    __syncthreads();
    unsigned s = (unsigned)ci * CAPG;
    unsigned e = pcur[ci];
    for (unsigned j = s + t; j < e; j += 256)
        atomicAdd(&lh[epart[j] >> 17], 1u);
    __syncthreads();
    unsigned* hrow = hist + (unsigned)ci * PSZ;
    for (int i = t; i < PSZ; i += 256) hrow[i] = lh[i];
}

// ---------- K3: scan chunk counts per bin -> chunk bases (in place) + deg + bsum ----------
__global__ __launch_bounds__(256) void k_colscan(unsigned* __restrict__ hist,
                                                 unsigned* __restrict__ deg,
                                                 unsigned* __restrict__ bsum) {
    __shared__ unsigned W[4];
    int t = threadIdx.x;
    int gid = blockIdx.x * 256 + t;
    unsigned run = 0;
    if (gid < NN) {
        int p = gid / PSZ, i = gid % PSZ;
        #pragma unroll
        for (int c = 0; c < NGRP; ++c) {
            unsigned idx = (unsigned)(p * NGRP + c) * PSZ + i;
            unsigned v = hist[idx];
            hist[idx] = run;
            run += v;
        }
        deg[gid] = run;
    }
    unsigned d = (gid < NN) ? run : 0u;
    #pragma unroll
    for (int off = 1; off < 64; off <<= 1) d += __shfl_xor(d, off);
    if ((t & 63) == 0) W[t >> 6] = d;
    __syncthreads();
    if (t == 0) bsum[blockIdx.x] = W[0] + W[1] + W[2] + W[3];
}

// ---------- K4: exclusive scan of block sums (1 block) ----------
__global__ __launch_bounds__(512) void k_bscan(unsigned* __restrict__ bsum) {
    __shared__ unsigned S[512];
    int t = threadIdx.x;
    unsigned v = (t < NBLK) ? bsum[t] : 0u;
    S[t] = v;
    __syncthreads();
    for (int off = 1; off < 512; off <<= 1) {
        unsigned u = (t >= off) ? S[t - off] : 0u;
        __syncthreads();
        S[t] += u;
        __syncthreads();
    }
    if (t < NBLK) bsum[t] = S[t] - v;   // exclusive prefix
}

// ---------- K5: per-block scan -> cursor[i] = rowptr[i+1] (inclusive), dinv ----------
__global__ void k_cscan(const unsigned* __restrict__ deg, const unsigned* __restrict__ bsum,
                        unsigned* __restrict__ cursor, float* __restrict__ dinv) {
    __shared__ unsigned S[256];
    int t = threadIdx.x;
    int i = blockIdx.x * 256 + t;
    unsigned d = (i < NN) ? deg[i] : 0u;
    S[t] = d;
    __syncthreads();
    for (int off = 1; off < 256; off <<= 1) {
        unsigned u = (t >= off) ? S[t - off] : 0u;
        __syncthreads();
        S[t] += u;
        __syncthreads();
    }
    if (i < NN) {
        cursor[i] = bsum[blockIdx.x] + S[t];       // inclusive = rowptr[i+1]
        dinv[i] = rsqrtf((float)(d + 1u));
    }
}

// ---------- K6: place edges via LDS cursors (no global atomics) ----------
__global__ __launch_bounds__(256) void k_place(const unsigned* __restrict__ pcur,
                                               const unsigned* __restrict__ epart,
                                               const unsigned* __restrict__ hist,
                                               const unsigned* __restrict__ cursor,
                                               int* __restrict__ ecol) {
    __shared__ unsigned lcur[PSZ];
    int p = blockIdx.x & 7;
    int g = blockIdx.x >> 3;
    int ci = p * NGRP + g;
    int t = threadIdx.x;
    int pb = p * PSZ;
    const unsigned* hrow = hist + (unsigned)ci * PSZ;
    for (int i = t; i < PSZ; i += 256) {
        int gi = pb + i;
        unsigned rowstart = gi ? cursor[gi - 1] : 0u;
        lcur[i] = rowstart + hrow[i];
    }
    __syncthreads();
    unsigned s = (unsigned)ci * CAPG;
    unsigned e = pcur[ci];
    for (unsigned j = s + t; j < e; j += 256) {
        unsigned v = epart[j];
        unsigned pos = atomicAdd(&lcur[v >> 17], 1u);
        ecol[pos] = (int)(v & SRCMASK);
    }
}

// ---------- K7: h1h = fp16((X @ W1) * dinv[row]) — 64-row LDS tile, 6 blocks/CU ----------
__global__ __launch_bounds__(256) void k_gemm1(const float* __restrict__ X,
                                               const float* __restrict__ W1,
                                               const float* __restrict__ dinv,
                                               __half2* __restrict__ h1h) {
    __shared__ float Xs[32][65];
    __shared__ float4 Ws[1024];   // W1 as float4: [256 k][4 colgroups]
    int tid = threadIdx.x;
    const float4* W14 = (const float4*)W1;
    for (int i = tid; i < 1024; i += 256) Ws[i] = W14[i];

    int rowbase = blockIdx.x * 64;
    int q  = tid >> 2;      // 0..63 (row within tile)
    int cg = tid & 3;       // col group (4 floats)
    float4 acc = make_float4(0.f, 0.f, 0.f, 0.f);

    for (int kt = 0; kt < 8; ++kt) {
        __syncthreads();
        // stage 64 rows x 32 k (512 float4, 2 per thread)
        #pragma unroll
        for (int it = 0; it < 2; ++it) {
            int fl = tid + it * 256;       // 0..511
            int rl = fl >> 3;              // row 0..63 (8 float4 per row-chunk)
            int c4 = (fl & 7) << 2;        // 0..28
            int gr = rowbase + rl;
            float4 v = make_float4(0.f, 0.f, 0.f, 0.f);
            if (gr < NN) v = *(const float4*)(X + (size_t)gr * FIN + kt * 32 + c4);
            Xs[c4 + 0][rl] = v.x;
            Xs[c4 + 1][rl] = v.y;
            Xs[c4 + 2][rl] = v.z;
            Xs[c4 + 3][rl] = v.w;
        }
        __syncthreads();
        #pragma unroll
        for (int kk = 0; kk < 32; ++kk) {
            float4 w4 = Ws[(kt * 32 + kk) * 4 + cg];
            float xv = Xs[kk][q];
            acc.x += xv * w4.x;
            acc.y += xv * w4.y;
            acc.z += xv * w4.z;
            acc.w += xv * w4.w;
        }
    }
    int r = rowbase + q;
    if (r < NN) {
        float dv = dinv[r];
        union { __half2 h[2]; uint2 u; } pk;
        pk.h[0] = __floats2half2_rn(acc.x * dv, acc.y * dv);
        pk.h[1] = __floats2half2_rn(acc.z * dv, acc.w * dv);
        *(uint2*)(h1h + (size_t)r * 8 + cg * 2) = pk.u;
    }
}

// ---------- K8: fused gather-1 + gemm2 — node per 8-lane group ----------
// One coalesced ecol load per lane; indices shuffle-distributed within the group.
__global__ __launch_bounds__(256) void k_gathm(const unsigned* __restrict__ cursor,
                                               const int* __restrict__ ecol,
                                               const float* __restrict__ dinv,
                                               const float* __restrict__ b1,
                                               const float* __restrict__ W2,
                                               const __half2* __restrict__ h1h,
                                               __half2* __restrict__ h2h) {
    __shared__ float Ws[512];   // W2 [16][32]
    __shared__ float B1[16];
    int tid = threadIdx.x;
    Ws[tid] = W2[tid];
    Ws[tid + 256] = W2[tid + 256];
    if (tid < 16) B1[tid] = b1[tid];
    __syncthreads();
    int lane = tid & 63;
    int grp = lane >> 3, f2 = lane & 7;
    int gb = lane & 56;
    int node = blockIdx.x * 32 + (tid >> 6) * 8 + grp;
    unsigned s = node ? cursor[node - 1] : 0u;
    unsigned e = cursor[node];
    float2 acc = __half22float2(h1h[(size_t)node * 8 + f2]);   // self term
    for (unsigned j = s; j < e; j += 8) {
        unsigned jj = j + (unsigned)f2;
        int myc = ecol[jj < e ? jj : j];
        int cq[8];
        #pragma unroll
        for (int q = 0; q < 8; ++q) cq[q] = __shfl(myc, gb + q);
        float2 a[8];
        #pragma unroll
        for (int q = 0; q < 8; ++q)
            a[q] = __half22float2(h1h[(size_t)cq[q] * 8 + f2]);
        #pragma unroll
        for (int q = 0; q < 8; ++q) {
            float m = (j + q < e) ? 1.f : 0.f;
            acc.x += m * a[q].x;
            acc.y += m * a[q].y;
        }
    }
    float dv = dinv[node];
    float r0 = fmaxf(acc.x * dv + B1[2 * f2], 0.f);
    float r1 = fmaxf(acc.y * dv + B1[2 * f2 + 1], 0.f);
    float rv[16];
    #pragma unroll
    for (int q = 0; q < 8; ++q) {
        rv[2 * q]     = __shfl(r0, gb + q);
        rv[2 * q + 1] = __shfl(r1, gb + q);
    }
    float o0x = 0.f, o0y = 0.f, o1x = 0.f, o1y = 0.f;
    #pragma unroll
    for (int q = 0; q < 16; ++q) {
        float r = rv[q];
        o0x += r * Ws[q * 32 + 2 * f2];
        o0y += r * Ws[q * 32 + 2 * f2 + 1];
        o1x += r * Ws[q * 32 + 2 * f2 + 16];
        o1y += r * Ws[q * 32 + 2 * f2 + 17];
    }
    h2h[(size_t)node * 16 + f2]     = __floats2half2_rn(o0x * dv, o0y * dv);
    h2h[(size_t)node * 16 + f2 + 8] = __floats2half2_rn(o1x * dv, o1y * dv);
}

// ---------- K9: gather layer 2 — node per 16-lane group, 16 edges in flight ----------
__global__ __launch_bounds__(256) void k_gath2(const unsigned* __restrict__ cursor,
                                               const int* __restrict__ ecol,
                                               const float* __restrict__ dinv,
                                               const float* __restrict__ b2,
                                               const __half2* __restrict__ h2h,
                                               __half2* __restrict__ out2h) {
    int tid = threadIdx.x;
    int lane = tid & 63;
    int grp = lane >> 4, f2 = lane & 15;
    int gb = lane & 48;
    int node = blockIdx.x * 16 + (tid >> 6) * 4 + grp;
    unsigned s = node ? cursor[node - 1] : 0u;
    unsigned e = cursor[node];
    float2 acc = __half22float2(h2h[(size_t)node * 16 + f2]);  // self term
    for (unsigned j = s; j < e; j += 16) {
        unsigned jj = j + (unsigned)f2;
        int myc = ecol[jj < e ? jj : j];
        int cq[16];
        #pragma unroll
        for (int q = 0; q < 16; ++q) cq[q] = __shfl(myc, gb + q);
        float2 a[16];
        #pragma unroll
        for (int q = 0; q < 16; ++q)
            a[q] = __half22float2(h2h[(size_t)cq[q] * 16 + f2]);
        #pragma unroll
        for (int q = 0; q < 16; ++q) {
            float m = (j + q < e) ? 1.f : 0.f;
            acc.x += m * a[q].x;
            acc.y += m * a[q].y;
        }
    }
    float dv = dinv[node];
    float2 b = ((const float2*)b2)[f2];
    out2h[(size_t)node * 16 + f2] =
        __floats2half2_rn(acc.x * dv + b.x, acc.y * dv + b.y);
}

// ---------- K10: conv1d(32->64, k=3, pad 1) + global max (fp16 input) ----------
#define NPB 256
__global__ __launch_bounds__(256) void k_conv(const __half2* __restrict__ h2f,
                                              const float* __restrict__ cw,
                                              unsigned* __restrict__ pool) {
    __shared__ float Hs[NPB + 2][33];
    __shared__ float Wt[3 * 32 * 64];
    __shared__ float4 Ms[4][16];
    int tid = threadIdx.x;
    int base = blockIdx.x * NPB;
    for (int idx = tid; idx < 6144; idx += 256) {
        int o = idx / 96, r = idx % 96, ci = r / 3, k = r % 3;
        Wt[(k * 32 + ci) * 64 + o] = cw[idx];
    }
    // stage rows base-1 .. base+256 from fp16: 4 x uint4 per row (uint4 = 4 half2)
    for (int idx = tid; idx < (NPB + 2) * 4; idx += 256) {
        int j = idx >> 2, qt = idx & 3;
        int g = base + j - 1;
        if (g >= 0 && g < NN) {
            uint4 v = *(const uint4*)(h2f + (size_t)g * 16 + qt * 4);
            const __half2* hp = (const __half2*)&v;
            #pragma unroll
            for (int q = 0; q < 4; ++q) {
                float2 f = __half22float2(hp[q]);
                Hs[j][qt * 8 + 2 * q]     = f.x;
                Hs[j][qt * 8 + 2 * q + 1] = f.y;
            }
        } else {
            #pragma unroll
            for (int q = 0; q < 8; ++q) Hs[j][qt * 8 + q] = 0.f;
        }
    }
    __syncthreads();

    int o4 = (tid & 15) * 4;
    int ng = tid >> 4;
    float4 acc[16] = {};
    for (int ci = 0; ci < 32; ++ci) {
        float h[18];
        #pragma unroll
        for (int j = 0; j < 18; ++j) h[j] = Hs[ng * 16 + j][ci];
        #pragma unroll
        for (int k = 0; k < 3; ++k) {
            float4 w = *(const float4*)&Wt[(k * 32 + ci) * 64 + o4];
            #pragma unroll
            for (int i = 0; i < 16; ++i) {
                float hv = h[i + k];
                acc[i].x += hv * w.x;
                acc[i].y += hv * w.y;
                acc[i].z += hv * w.z;
                acc[i].w += hv * w.w;
            }
        }
    }
    const float NI = -3.0e38f;
    float4 m4 = make_float4(NI, NI, NI, NI);
    #pragma unroll
    for (int i = 0; i < 16; ++i) {
        if (base + ng * 16 + i < NN) {
            m4.x = fmaxf(m4.x, acc[i].x);
            m4.y = fmaxf(m4.y, acc[i].y);
            m4.z = fmaxf(m4.z, acc[i].z);
            m4.w = fmaxf(m4.w, acc[i].w);
        }
    }
    #pragma unroll
    for (int off = 16; off <= 32; off <<= 1) {
        m4.x = fmaxf(m4.x, __shfl_xor(m4.x, off));
        m4.y = fmaxf(m4.y, __shfl_xor(m4.y, off));
        m4.z = fmaxf(m4.z, __shfl_xor(m4.z, off));
        m4.w = fmaxf(m4.w, __shfl_xor(m4.w, off));
    }
    int lane = tid & 63, wv = tid >> 6;
    if (lane < 16) Ms[wv][lane] = m4;
    __syncthreads();
    if (tid < 16) {
        float4 a = Ms[0][tid], b = Ms[1][tid], c = Ms[2][tid], d = Ms[3][tid];
        a.x = fmaxf(fmaxf(a.x, b.x), fmaxf(c.x, d.x));
        a.y = fmaxf(fmaxf(a.y, b.y), fmaxf(c.y, d.y));
        a.z = fmaxf(fmaxf(a.z, b.z), fmaxf(c.z, d.z));
        a.w = fmaxf(fmaxf(a.w, b.w), fmaxf(c.w, d.w));
        int o = tid * 4;
        atomicMax(&pool[o + 0], enc_f(a.x));
        atomicMax(&pool[o + 1], enc_f(a.y));
        atomicMax(&pool[o + 2], enc_f(a.z));
        atomicMax(&pool[o + 3], enc_f(a.w));
    }
}

// ---------- K11: out = (pooled + conv_b) @ fc_w^T + fc_b ----------
__global__ void k_fc(const unsigned* __restrict__ pool, const float* __restrict__ cb,
                     const float* __restrict__ fw, const float* __restrict__ fb,
                     float* __restrict__ out) {
    __shared__ float P[64];
    int tid = threadIdx.x;
    if (tid < 64) P[tid] = dec_f(pool[tid]) + cb[tid];
    __syncthreads();
    int j = blockIdx.x * 256 + tid;
    if (j >= NC) return;
    float s = fb[j];
    const float4* wr = (const float4*)(fw + (size_t)j * CO);
    #pragma unroll
    for (int c = 0; c < 16; ++c) {
        float4 w = wr[c];
        s += P[c * 4 + 0] * w.x + P[c * 4 + 1] * w.y +
             P[c * 4 + 2] * w.z + P[c * 4 + 3] * w.w;
    }
    out[j] = s;
}

extern "C" void kernel_launch(void* const* d_in, const int* in_sizes, int n_in,
                              void* d_out, int out_size, void* d_ws, size_t ws_size,
                              hipStream_t stream) {
    const float* x  = (const float*)d_in[0];
    const int*   ei = (const int*)d_in[1];
    const float* W1 = (const float*)d_in[2];
    const float* b1 = (const float*)d_in[3];
    const float* W2 = (const float*)d_in[4];
    const float* b2 = (const float*)d_in[5];
    const float* cw = (const float*)d_in[6];
    const float* cb = (const float*)d_in[7];
    const float* fw = (const float*)d_in[8];
    const float* fb = (const float*)d_in[9];

    float* ws = (float*)d_ws;
    float*    dinv   = ws + OFF_DINV;
    unsigned* cursor = (unsigned*)(ws + OFF_CUR);
    unsigned* deg    = (unsigned*)(ws + OFF_DEG);
    int*      ecol   = (int*)(ws + OFF_ECOL);
    unsigned* pcur   = (unsigned*)(ws + OFF_MISC);
    unsigned* pool   = pcur + 256;
    unsigned* bsum   = pcur + 320;
    unsigned* epart  = (unsigned*)(ws + OFF_EPART);
    unsigned* hist   = (unsigned*)(ws + OFF_HIST);
    __half2*  h1h    = (__half2*)(ws + OFF_H1S);
    __half2*  h2h    = (__half2*)(ws + OFF_H2S);
    __half2*  out2h  = (__half2*)(ws + OFF_OUT2H);

    k_init   <<<1, 256, 0, stream>>>(pcur, pool);
    k_bucket <<<NE / (256 * BK), 256, 0, stream>>>(ei, pcur, epart);        // 625
    k_hist   <<<NPART * NGRP, 256, 0, stream>>>(pcur, epart, hist);         // 256
    k_colscan<<<NBLK, 256, 0, stream>>>(hist, deg, bsum);
    k_bscan  <<<1, 512, 0, stream>>>(bsum);
    k_cscan  <<<NBLK, 256, 0, stream>>>(deg, bsum, cursor, dinv);
    k_place  <<<NPART * NGRP, 256, 0, stream>>>(pcur, epart, hist, cursor, ecol);
    k_gemm1  <<<GBLK, 256, 0, stream>>>(x, W1, dinv, h1h);                  // 1563
    k_gathm  <<<NN / 32, 256, 0, stream>>>(cursor, ecol, dinv, b1, W2, h1h, h2h);   // 3125
    k_gath2  <<<NN / 16, 256, 0, stream>>>(cursor, ecol, dinv, b2, h2h, out2h);     // 6250
    k_conv   <<<(NN + NPB - 1) / NPB, 256, 0, stream>>>(out2h, cw, pool);
    k_fc     <<<4, 256, 0, stream>>>(pool, cb, fw, fb, (float*)d_out);
}

// Round 20
// 246.209 us; speedup vs baseline: 1.0021x; 1.0021x over previous
//
#include <hip/hip_runtime.h>
#include <hip/hip_bf16.h>
#include <hip/hip_fp16.h>

#define NN 100000
#define NE 3200000
#define FIN 256
#define F1 16
#define F2 32
#define CO 64
#define NC 1000
#define NBLK 391   /* ceil(NN/256) */
#define GBLK 1563  /* ceil(NN/64) gemm1 grid (64-row tiles) */
#define NPART 8
#define NGRP 32    /* sub-segments (groups) per partition */
#define CAPG 16384 /* fixed capacity per (partition,group) sub-segment */
#define PSZ 12500  /* NN / NPART */
#define BK 20      /* edges per thread in bucket; 625 blocks * 256 * 20 = NE */
#define SRCMASK 0x1FFFFu   /* low 17 bits = src; high bits = dst_local */

// workspace layout (float offsets) — total 10,896,384 floats = 43.6 MB
#define OFF_DINV 0
#define OFF_CUR  100352
#define OFF_DEG  200704
#define OFF_ECOL 301056
#define OFF_MISC 3501056    /* pcur[256]@0, pool[64]@256, bsum[391]@320 (ends 711 < 1024) */
#define OFF_EPART 3502080   /* u32[256*16384] = 4,194,304 -> ends 7,696,384 */
#define OFF_HIST  7696384   /* u32[8*32*12500] = 3.2M -> ends 10,896,384 */
#define OFF_H1S   3502080   /* fp16, 800K floats (ends 4,302,080); overlays epart (dead after place) */
#define OFF_H2S   4302080   /* fp16, 1.6M floats (ends 5,902,080); overlays epart (dead after place) */
#define OFF_OUT2H 5902080   /* fp16, 1.6M floats (ends 7,502,080); overlays epart tail (dead after place) */

__device__ __forceinline__ unsigned enc_f(float f) {
    unsigned u = __float_as_uint(f);
    return (u & 0x80000000u) ? ~u : (u | 0x80000000u);
}
__device__ __forceinline__ float dec_f(unsigned u) {
    return (u & 0x80000000u) ? __uint_as_float(u & 0x7fffffffu) : __uint_as_float(~u);
}

// ---------- K0: init fixed sub-segment cursors + zero pool ----------
__global__ void k_init(unsigned* __restrict__ pcur, unsigned* __restrict__ pool) {
    int t = threadIdx.x;
    pcur[t] = (unsigned)t * CAPG;
    if (t < 64) pool[t] = 0u;
}

// ---------- K1: bucket edges into fixed-capacity (p,g) sub-segments, packed u32 ----------
__global__ __launch_bounds__(256) void k_bucket(const int* __restrict__ ei,
                                                unsigned* __restrict__ pcur,
                                                unsigned* __restrict__ epart) {
    __shared__ unsigned wcnt[4][8];
    __shared__ unsigned woff[4][8];
    int t = threadIdx.x, lane = t & 63, w = t >> 6;
    int g = blockIdx.x & (NGRP - 1);
    int base = blockIdx.x * (256 * BK) + t;
    int dst[BK], src[BK];
    #pragma unroll
    for (int k = 0; k < BK; ++k) {
        dst[k] = ei[NE + base + k * 256];
        src[k] = ei[base + k * 256];
    }
    unsigned long long lt = (lane == 63) ? 0x7fffffffffffffffull
                                         : ((1ull << lane) - 1ull);
    // sweep 1: per-wave per-bin counts (lane b tracks bin b)
    unsigned cnt = 0;
    #pragma unroll
    for (int k = 0; k < BK; ++k) {
        int bin = (unsigned)dst[k] / PSZ;
        #pragma unroll
        for (int b = 0; b < 8; ++b) {
            unsigned long long m = __ballot(bin == b);
            if (lane == b) cnt += (unsigned)__popcll(m);
        }
    }
    if (lane < 8) wcnt[w][lane] = cnt;
    __syncthreads();
    if (t < 8) {
        unsigned c0 = wcnt[0][t], c1 = wcnt[1][t], c2 = wcnt[2][t], c3 = wcnt[3][t];
        unsigned b = atomicAdd(&pcur[t * NGRP + g], c0 + c1 + c2 + c3);
        woff[0][t] = b;
        woff[1][t] = b + c0;
        woff[2][t] = b + c0 + c1;
        woff[3][t] = b + c0 + c1 + c2;
    }
    __syncthreads();
    unsigned run = (lane < 8) ? woff[w][lane] : 0u;
    // sweep 2: place packed (dst_local<<17 | src)
    #pragma unroll
    for (int k = 0; k < BK; ++k) {
        int bin = (unsigned)dst[k] / PSZ;
        unsigned long long mym = 0;
        unsigned myrun = 0;
        #pragma unroll
        for (int b = 0; b < 8; ++b) {
            unsigned long long m = __ballot(bin == b);
            unsigned r = __shfl(run, b);
            if (bin == b) { mym = m; myrun = r; }
            if (lane == b) run += (unsigned)__popcll(m);
        }
        unsigned pos = myrun + (unsigned)__popcll(mym & lt);
        epart[pos] = ((unsigned)(dst[k] - bin * PSZ) << 17) | (unsigned)src[k];
    }
}

// ---------- K2: per-(p,g) LDS histograms -> hist[p][g][i] ----------
__global__ __launch_bounds__(256) void k_hist(const unsigned* __restrict__ pcur,
                                              const unsigned* __restrict__ epart,
                                              unsigned* __restrict__ hist) {
    __shared__ unsigned lh[PSZ];
    int p = blockIdx.x & 7;
    int g = blockIdx.x >> 3;               // 0..NGRP-1
    int ci = p * NGRP + g;
    int t = threadIdx.x;
    for (int i = t; i < PSZ; i += 256) lh[i] = 0;
    __syncthreads();
    unsigned s = (unsigned)ci * CAPG;
    unsigned e = pcur[ci];
    for (unsigned j = s + t; j < e; j += 256)
        atomicAdd(&lh[epart[j] >> 17], 1u);
    __syncthreads();
    unsigned* hrow = hist + (unsigned)ci * PSZ;
    for (int i = t; i < PSZ; i += 256) hrow[i] = lh[i];
}

// ---------- K3: scan chunk counts per bin -> chunk bases (in place) + deg + bsum ----------
__global__ __launch_bounds__(256) void k_colscan(unsigned* __restrict__ hist,
                                                 unsigned* __restrict__ deg,
                                                 unsigned* __restrict__ bsum) {
    __shared__ unsigned W[4];
    int t = threadIdx.x;
    int gid = blockIdx.x * 256 + t;
    unsigned run = 0;
    if (gid < NN) {
        int p = gid / PSZ, i = gid % PSZ;
        #pragma unroll
        for (int c = 0; c < NGRP; ++c) {
            unsigned idx = (unsigned)(p * NGRP + c) * PSZ + i;
            unsigned v = hist[idx];
            hist[idx] = run;
            run += v;
        }
        deg[gid] = run;
    }
    unsigned d = (gid < NN) ? run : 0u;
    #pragma unroll
    for (int off = 1; off < 64; off <<= 1) d += __shfl_xor(d, off);
    if ((t & 63) == 0) W[t >> 6] = d;
    __syncthreads();
    if (t == 0) bsum[blockIdx.x] = W[0] + W[1] + W[2] + W[3];
}

// ---------- K4: exclusive scan of block sums (1 block) ----------
__global__ __launch_bounds__(512) void k_bscan(unsigned* __restrict__ bsum) {
    __shared__ unsigned S[512];
    int t = threadIdx.x;
    unsigned v = (t < NBLK) ? bsum[t] : 0u;
    S[t] = v;
    __syncthreads();
    for (int off = 1; off < 512; off <<= 1) {
        unsigned u = (t >= off) ? S[t - off] : 0u;
        __syncthreads();
        S[t] += u;
        __syncthreads();
    }
    if (t < NBLK) bsum[t] = S[t] - v;   // exclusive prefix
}

// ---------- K5: per-block scan -> cursor[i] = rowptr[i+1] (inclusive), dinv ----------
__global__ void k_cscan(const unsigned* __restrict__ deg, const unsigned* __restrict__ bsum,
                        unsigned* __restrict__ cursor, float* __restrict__ dinv) {
    __shared__ unsigned S[256];
    int t = threadIdx.x;
    int i = blockIdx.x * 256 + t;
    unsigned d = (i < NN) ? deg[i] : 0u;
    S[t] = d;
    __syncthreads();
    for (int off = 1; off < 256; off <<= 1) {
        unsigned u = (t >= off) ? S[t - off] : 0u;
        __syncthreads();
        S[t] += u;
        __syncthreads();
    }
    if (i < NN) {
        cursor[i] = bsum[blockIdx.x] + S[t];       // inclusive = rowptr[i+1]
        dinv[i] = rsqrtf((float)(d + 1u));
    }
}

// ---------- K6: place edges via LDS cursors (no global atomics) ----------
__global__ __launch_bounds__(256) void k_place(const unsigned* __restrict__ pcur,
                                               const unsigned* __restrict__ epart,
                                               const unsigned* __restrict__ hist,
                                               const unsigned* __restrict__ cursor,
                                               int* __restrict__ ecol) {
    __shared__ unsigned lcur[PSZ];
    int p = blockIdx.x & 7;
    int g = blockIdx.x >> 3;
    int ci = p * NGRP + g;
    int t = threadIdx.x;
    int pb = p * PSZ;
    const unsigned* hrow = hist + (unsigned)ci * PSZ;
    for (int i = t; i < PSZ; i += 256) {
        int gi = pb + i;
        unsigned rowstart = gi ? cursor[gi - 1] : 0u;
        lcur[i] = rowstart + hrow[i];
    }
    __syncthreads();
    unsigned s = (unsigned)ci * CAPG;
    unsigned e = pcur[ci];
    for (unsigned j = s + t; j < e; j += 256) {
        unsigned v = epart[j];
        unsigned pos = atomicAdd(&lcur[v >> 17], 1u);
        ecol[pos] = (int)(v & SRCMASK);
    }
}

// ---------- K7: h1h = fp16((X @ W1) * dinv[row]) — 64-row tile + register prefetch ----------
__global__ __launch_bounds__(256) void k_gemm1(const float* __restrict__ X,
                                               const float* __restrict__ W1,
                                               const float* __restrict__ dinv,
                                               __half2* __restrict__ h1h) {
    __shared__ float Xs[32][65];
    __shared__ float4 Ws[1024];   // W1 as float4: [256 k][4 colgroups]
    int tid = threadIdx.x;
    const float4* W14 = (const float4*)W1;
    for (int i = tid; i < 1024; i += 256) Ws[i] = W14[i];

    int rowbase = blockIdx.x * 64;
    int q  = tid >> 2;      // 0..63 (row within tile)
    int cg = tid & 3;       // col group (4 floats)

    // staging assignment: thread covers float4 slots {tid, tid+256} of 512
    int fl1 = tid + 256;
    int rl0 = tid >> 3,  c40 = (tid & 7) << 2;
    int rl1 = fl1 >> 3,  c41 = (fl1 & 7) << 2;
    int gr0 = rowbase + rl0, gr1 = rowbase + rl1;
    bool ok0 = gr0 < NN, ok1 = gr1 < NN;
    const float* p0 = X + (size_t)(ok0 ? gr0 : 0) * FIN + c40;
    const float* p1 = X + (size_t)(ok1 ? gr1 : 0) * FIN + c41;
    const float4 z = make_float4(0.f, 0.f, 0.f, 0.f);
    float4 va = ok0 ? *(const float4*)p0 : z;
    float4 vb = ok1 ? *(const float4*)p1 : z;
    float4 acc = z;

    for (int kt = 0; kt < 8; ++kt) {
        __syncthreads();
        Xs[c40 + 0][rl0] = va.x; Xs[c40 + 1][rl0] = va.y;
        Xs[c40 + 2][rl0] = va.z; Xs[c40 + 3][rl0] = va.w;
        Xs[c41 + 0][rl1] = vb.x; Xs[c41 + 1][rl1] = vb.y;
        Xs[c41 + 2][rl1] = vb.z; Xs[c41 + 3][rl1] = vb.w;
        if (kt < 7) {             // prefetch next k-tile while this one computes
            int off = (kt + 1) * 32;
            va = ok0 ? *(const float4*)(p0 + off) : z;
            vb = ok1 ? *(const float4*)(p1 + off) : z;
        }
        __syncthreads();
        #pragma unroll
        for (int kk = 0; kk < 32; ++kk) {
            float4 w4 = Ws[(kt * 32 + kk) * 4 + cg];
            float xv = Xs[kk][q];
            acc.x += xv * w4.x;
            acc.y += xv * w4.y;
            acc.z += xv * w4.z;
            acc.w += xv * w4.w;
        }
    }
    int r = rowbase + q;
    if (r < NN) {
        float dv = dinv[r];
        union { __half2 h[2]; uint2 u; } pk;
        pk.h[0] = __floats2half2_rn(acc.x * dv, acc.y * dv);
        pk.h[1] = __floats2half2_rn(acc.z * dv, acc.w * dv);
        *(uint2*)(h1h + (size_t)r * 8 + cg * 2) = pk.u;
    }
}

// ---------- K8: fused gather-1 + gemm2 — node per 8-lane group ----------
// One coalesced ecol load per lane; indices shuffle-distributed within the group.
__global__ __launch_bounds__(256) void k_gathm(const unsigned* __restrict__ cursor,
                                               const int* __restrict__ ecol,
                                               const float* __restrict__ dinv,
                                               const float* __restrict__ b1,
                                               const float* __restrict__ W2,
                                               const __half2* __restrict__ h1h,
                                               __half2* __restrict__ h2h) {
    __shared__ float Ws[512];   // W2 [16][32]
    __shared__ float B1[16];
    int tid = threadIdx.x;
    Ws[tid] = W2[tid];
    Ws[tid + 256] = W2[tid + 256];
    if (tid < 16) B1[tid] = b1[tid];
    __syncthreads();
    int lane = tid & 63;
    int grp = lane >> 3, f2 = lane & 7;
    int gb = lane & 56;
    int node = blockIdx.x * 32 + (tid >> 6) * 8 + grp;
    unsigned s = node ? cursor[node - 1] : 0u;
    unsigned e = cursor[node];
    float2 acc = __half22float2(h1h[(size_t)node * 8 + f2]);   // self term
    for (unsigned j = s; j < e; j += 8) {
        unsigned jj = j + (unsigned)f2;
        int myc = ecol[jj < e ? jj : j];
        int cq[8];
        #pragma unroll
        for (int q = 0; q < 8; ++q) cq[q] = __shfl(myc, gb + q);
        float2 a[8];
        #pragma unroll
        for (int q = 0; q < 8; ++q)
            a[q] = __half22float2(h1h[(size_t)cq[q] * 8 + f2]);
        #pragma unroll
        for (int q = 0; q < 8; ++q) {
            float m = (j + q < e) ? 1.f : 0.f;
            acc.x += m * a[q].x;
            acc.y += m * a[q].y;
        }
    }
    float dv = dinv[node];
    float r0 = fmaxf(acc.x * dv + B1[2 * f2], 0.f);
    float r1 = fmaxf(acc.y * dv + B1[2 * f2 + 1], 0.f);
    float rv[16];
    #pragma unroll
    for (int q = 0; q < 8; ++q) {
        rv[2 * q]     = __shfl(r0, gb + q);
        rv[2 * q + 1] = __shfl(r1, gb + q);
    }
    float o0x = 0.f, o0y = 0.f, o1x = 0.f, o1y = 0.f;
    #pragma unroll
    for (int q = 0; q < 16; ++q) {
        float r = rv[q];
        o0x += r * Ws[q * 32 + 2 * f2];
        o0y += r * Ws[q * 32 + 2 * f2 + 1];
        o1x += r * Ws[q * 32 + 2 * f2 + 16];
        o1y += r * Ws[q * 32 + 2 * f2 + 17];
    }
    h2h[(size_t)node * 16 + f2]     = __floats2half2_rn(o0x * dv, o0y * dv);
    h2h[(size_t)node * 16 + f2 + 8] = __floats2half2_rn(o1x * dv, o1y * dv);
}

// ---------- K9: gather layer 2 — node per 16-lane group, 16 edges in flight ----------
__global__ __launch_bounds__(256) void k_gath2(const unsigned* __restrict__ cursor,
                                               const int* __restrict__ ecol,
                                               const float* __restrict__ dinv,
                                               const float* __restrict__ b2,
                                               const __half2* __restrict__ h2h,
                                               __half2* __restrict__ out2h) {
    int tid = threadIdx.x;
    int lane = tid & 63;
    int grp = lane >> 4, f2 = lane & 15;
    int gb = lane & 48;
    int node = blockIdx.x * 16 + (tid >> 6) * 4 + grp;
    unsigned s = node ? cursor[node - 1] : 0u;
    unsigned e = cursor[node];
    float2 acc = __half22float2(h2h[(size_t)node * 16 + f2]);  // self term
    for (unsigned j = s; j < e; j += 16) {
        unsigned jj = j + (unsigned)f2;
        int myc = ecol[jj < e ? jj : j];
        int cq[16];
        #pragma unroll
        for (int q = 0; q < 16; ++q) cq[q] = __shfl(myc, gb + q);
        float2 a[16];
        #pragma unroll
        for (int q = 0; q < 16; ++q)
            a[q] = __half22float2(h2h[(size_t)cq[q] * 16 + f2]);
        #pragma unroll
        for (int q = 0; q < 16; ++q) {
            float m = (j + q < e) ? 1.f : 0.f;
            acc.x += m * a[q].x;
            acc.y += m * a[q].y;
        }
    }
    float dv = dinv[node];
    float2 b = ((const float2*)b2)[f2];
    out2h[(size_t)node * 16 + f2] =
        __floats2half2_rn(acc.x * dv + b.x, acc.y * dv + b.y);
}

// ---------- K10: conv1d(32->64, k=3, pad 1) + global max (fp16 input) ----------
#define NPB 256
__global__ __launch_bounds__(256) void k_conv(const __half2* __restrict__ h2f,
                                              const float* __restrict__ cw,
                                              unsigned* __restrict__ pool) {
    __shared__ float Hs[NPB + 2][33];
    __shared__ float Wt[3 * 32 * 64];
    __shared__ float4 Ms[4][16];
    int tid = threadIdx.x;
    int base = blockIdx.x * NPB;
    for (int idx = tid; idx < 6144; idx += 256) {
        int o = idx / 96, r = idx % 96, ci = r / 3, k = r % 3;
        Wt[(k * 32 + ci) * 64 + o] = cw[idx];
    }
    // stage rows base-1 .. base+256 from fp16: 4 x uint4 per row (uint4 = 4 half2)
    for (int idx = tid; idx < (NPB + 2) * 4; idx += 256) {
        int j = idx >> 2, qt = idx & 3;
        int g = base + j - 1;
        if (g >= 0 && g < NN) {
            uint4 v = *(const uint4*)(h2f + (size_t)g * 16 + qt * 4);
            const __half2* hp = (const __half2*)&v;
            #pragma unroll
            for (int q = 0; q < 4; ++q) {
                float2 f = __half22float2(hp[q]);
                Hs[j][qt * 8 + 2 * q]     = f.x;
                Hs[j][qt * 8 + 2 * q + 1] = f.y;
            }
        } else {
            #pragma unroll
            for (int q = 0; q < 8; ++q) Hs[j][qt * 8 + q] = 0.f;
        }
    }
    __syncthreads();

    int o4 = (tid & 15) * 4;
    int ng = tid >> 4;
    float4 acc[16] = {};
    for (int ci = 0; ci < 32; ++ci) {
        float h[18];
        #pragma unroll
        for (int j = 0; j < 18; ++j) h[j] = Hs[ng * 16 + j][ci];
        #pragma unroll
        for (int k = 0; k < 3; ++k) {
            float4 w = *(const float4*)&Wt[(k * 32 + ci) * 64 + o4];
            #pragma unroll
            for (int i = 0; i < 16; ++i) {
                float hv = h[i + k];
                acc[i].x += hv * w.x;
                acc[i].y += hv * w.y;
                acc[i].z += hv * w.z;
                acc[i].w += hv * w.w;
            }
        }
    }
    const float NI = -3.0e38f;
    float4 m4 = make_float4(NI, NI, NI, NI);
    #pragma unroll
    for (int i = 0; i < 16; ++i) {
        if (base + ng * 16 + i < NN) {
            m4.x = fmaxf(m4.x, acc[i].x);
            m4.y = fmaxf(m4.y, acc[i].y);
            m4.z = fmaxf(m4.z, acc[i].z);
            m4.w = fmaxf(m4.w, acc[i].w);
        }
    }
    #pragma unroll
    for (int off = 16; off <= 32; off <<= 1) {
        m4.x = fmaxf(m4.x, __shfl_xor(m4.x, off));
        m4.y = fmaxf(m4.y, __shfl_xor(m4.y, off));
        m4.z = fmaxf(m4.z, __shfl_xor(m4.z, off));
        m4.w = fmaxf(m4.w, __shfl_xor(m4.w, off));
    }
    int lane = tid & 63, wv = tid >> 6;
    if (lane < 16) Ms[wv][lane] = m4;
    __syncthreads();
    if (tid < 16) {
        float4 a = Ms[0][tid], b = Ms[1][tid], c = Ms[2][tid], d = Ms[3][tid];
        a.x = fmaxf(fmaxf(a.x, b.x), fmaxf(c.x, d.x));
        a.y = fmaxf(fmaxf(a.y, b.y), fmaxf(c.y, d.y));
        a.z = fmaxf(fmaxf(a.z, b.z), fmaxf(c.z, d.z));
        a.w = fmaxf(fmaxf(a.w, b.w), fmaxf(c.w, d.w));
        int o = tid * 4;
        atomicMax(&pool[o + 0], enc_f(a.x));
        atomicMax(&pool[o + 1], enc_f(a.y));
        atomicMax(&pool[o + 2], enc_f(a.z));
        atomicMax(&pool[o + 3], enc_f(a.w));
    }
}

// ---------- K11: out = (pooled + conv_b) @ fc_w^T + fc_b ----------
__global__ void k_fc(const unsigned* __restrict__ pool, const float* __restrict__ cb,
                     const float* __restrict__ fw, const float* __restrict__ fb,
                     float* __restrict__ out) {
    __shared__ float P[64];
    int tid = threadIdx.x;
    if (tid < 64) P[tid] = dec_f(pool[tid]) + cb[tid];
    __syncthreads();
    int j = blockIdx.x * 256 + tid;
    if (j >= NC) return;
    float s = fb[j];
    const float4* wr = (const float4*)(fw + (size_t)j * CO);
    #pragma unroll
    for (int c = 0; c < 16; ++c) {
        float4 w = wr[c];
        s += P[c * 4 + 0] * w.x + P[c * 4 + 1] * w.y +
             P[c * 4 + 2] * w.z + P[c * 4 + 3] * w.w;
    }
    out[j] = s;
}

extern "C" void kernel_launch(void* const* d_in, const int* in_sizes, int n_in,
                              void* d_out, int out_size, void* d_ws, size_t ws_size,
                              hipStream_t stream) {
    const float* x  = (const float*)d_in[0];
    const int*   ei = (const int*)d_in[1];
    const float* W1 = (const float*)d_in[2];
    const float* b1 = (const float*)d_in[3];
    const float* W2 = (const float*)d_in[4];
    const float* b2 = (const float*)d_in[5];
    const float* cw = (const float*)d_in[6];
    const float* cb = (const float*)d_in[7];
    const float* fw = (const float*)d_in[8];
    const float* fb = (const float*)d_in[9];

    float* ws = (float*)d_ws;
    float*    dinv   = ws + OFF_DINV;
    unsigned* cursor = (unsigned*)(ws + OFF_CUR);
    unsigned* deg    = (unsigned*)(ws + OFF_DEG);
    int*      ecol   = (int*)(ws + OFF_ECOL);
    unsigned* pcur   = (unsigned*)(ws + OFF_MISC);
    unsigned* pool   = pcur + 256;
    unsigned* bsum   = pcur + 320;
    unsigned* epart  = (unsigned*)(ws + OFF_EPART);
    unsigned* hist   = (unsigned*)(ws + OFF_HIST);
    __half2*  h1h    = (__half2*)(ws + OFF_H1S);
    __half2*  h2h    = (__half2*)(ws + OFF_H2S);
    __half2*  out2h  = (__half2*)(ws + OFF_OUT2H);

    k_init   <<<1, 256, 0, stream>>>(pcur, pool);
    k_bucket <<<NE / (256 * BK), 256, 0, stream>>>(ei, pcur, epart);        // 625
    k_hist   <<<NPART * NGRP, 256, 0, stream>>>(pcur, epart, hist);         // 256
    k_colscan<<<NBLK, 256, 0, stream>>>(hist, deg, bsum);
    k_bscan  <<<1, 512, 0, stream>>>(bsum);
    k_cscan  <<<NBLK, 256, 0, stream>>>(deg, bsum, cursor, dinv);
    k_place  <<<NPART * NGRP, 256, 0, stream>>>(pcur, epart, hist, cursor, ecol);
    k_gemm1  <<<GBLK, 256, 0, stream>>>(x, W1, dinv, h1h);                  // 1563
    k_gathm  <<<NN / 32, 256, 0, stream>>>(cursor, ecol, dinv, b1, W2, h1h, h2h);   // 3125
    k_gath2  <<<NN / 16, 256, 0, stream>>>(cursor, ecol, dinv, b2, h2h, out2h);     // 6250
    k_conv   <<<(NN + NPB - 1) / NPB, 256, 0, stream>>>(out2h, cw, pool);
    k_fc     <<<4, 256, 0, stream>>>(pool, cb, fw, fb, (float*)d_out);
}